// Round 8
// baseline (2808.899 us; speedup 1.0000x reference)
//
#include <hip/hip_runtime.h>
#include <math.h>

// ---- problem dims ----
#define BN_ 650
#define T_ 48
#define V_ 3
#define T2_ 12
#define NROWS_ 7800            // BN_*T2_
#define MKV_ 31200             // BN_*T_
#define LOG2PI_ 1.8378770664093453f

typedef short s8v __attribute__((ext_vector_type(8)));
typedef float f4v __attribute__((ext_vector_type(4)));

__device__ __forceinline__ float b2f(unsigned short h) {
  return __uint_as_float(((unsigned)h) << 16);
}
__device__ __forceinline__ unsigned short f2b(float f) {
  unsigned u = __float_as_uint(f);
  return (unsigned short)((u + 0x7fffu + ((u >> 16) & 1u)) >> 16);
}

// ============================================================
// bf16 MFMA GEMM: C[M,512] = act(A[M,Kp] @ BT[512,Kp]^T + bias)(+res)
// BT pre-transposed [N][Kp] bf16.
// ============================================================
struct GZ {
  const unsigned short* A;
  const unsigned short* B;
  const float* bias;
  unsigned short* C;
  const unsigned short* res;
  int act;   // 0 none, 1 relu, 2 tanh
};

// ---- 128x128 tile, 256 thr, 4 waves (2x2) ----
template<int BM>
__global__ __launch_bounds__(256)
void gemm_bf16(GZ g0, GZ g1, int M, int Kp)
{
  constexpr int MF = BM / 32;
  constexpr int AU = BM / 32;
  __shared__ __align__(16) unsigned short As[2][BM * 72];
  __shared__ __align__(16) unsigned short Bs[2][128 * 72];
  GZ g = (blockIdx.z == 0) ? g0 : g1;
  const int tid = threadIdx.x;
  const int lane = tid & 63;
  const int wid = tid >> 6;
  const int wm = wid >> 1, wn = wid & 1;
  const int m0 = blockIdx.y * BM, n0 = blockIdx.x * 128;
  const int fr = lane & 15, fko = (lane >> 4) * 8;

  f4v acc[MF][4];
  #pragma unroll
  for (int i = 0; i < MF; i++)
    #pragma unroll
    for (int j = 0; j < 4; j++) acc[i][j] = (f4v){0.f, 0.f, 0.f, 0.f};

  const int steps = Kp >> 6;
  s8v ra[AU], rb[4];
  const s8v zed = (s8v){0,0,0,0,0,0,0,0};

  int arow[AU], akseg[AU], brow[4], bkseg[4];
  #pragma unroll
  for (int i = 0; i < AU; i++) { int gx = tid*AU + i; arow[i] = gx >> 3; akseg[i] = (gx & 7) * 8; }
  #pragma unroll
  for (int i = 0; i < 4; i++) { int gx = tid*4 + i; brow[i] = gx >> 3; bkseg[i] = (gx & 7) * 8; }

  #pragma unroll
  for (int i = 0; i < AU; i++)
    ra[i] = (m0 + arow[i] < M) ? *(const s8v*)(g.A + (size_t)(m0 + arow[i])*Kp + akseg[i]) : zed;
  #pragma unroll
  for (int i = 0; i < 4; i++)
    rb[i] = *(const s8v*)(g.B + (size_t)(n0 + brow[i])*Kp + bkseg[i]);
  #pragma unroll
  for (int i = 0; i < AU; i++) *(s8v*)&As[0][arow[i]*72 + akseg[i]] = ra[i];
  #pragma unroll
  for (int i = 0; i < 4; i++)  *(s8v*)&Bs[0][brow[i]*72 + bkseg[i]] = rb[i];
  __syncthreads();

  for (int s = 0; s < steps; s++) {
    if (s + 1 < steps) {
      const int ko = (s + 1) * 64;
      #pragma unroll
      for (int i = 0; i < AU; i++)
        ra[i] = (m0 + arow[i] < M) ? *(const s8v*)(g.A + (size_t)(m0 + arow[i])*Kp + ko + akseg[i]) : zed;
      #pragma unroll
      for (int i = 0; i < 4; i++)
        rb[i] = *(const s8v*)(g.B + (size_t)(n0 + brow[i])*Kp + ko + bkseg[i]);
    }
    const int buf = s & 1;
    #pragma unroll
    for (int kk = 0; kk < 2; kk++) {
      s8v af[MF], bfr[4];
      #pragma unroll
      for (int mm = 0; mm < MF; mm++)
        af[mm] = *(const s8v*)&As[buf][(wm*(BM/2) + mm*16 + fr)*72 + kk*32 + fko];
      #pragma unroll
      for (int nn = 0; nn < 4; nn++)
        bfr[nn] = *(const s8v*)&Bs[buf][(wn*64 + nn*16 + fr)*72 + kk*32 + fko];
      #pragma unroll
      for (int mm = 0; mm < MF; mm++)
        #pragma unroll
        for (int nn = 0; nn < 4; nn++)
          acc[mm][nn] = __builtin_amdgcn_mfma_f32_16x16x32_bf16(af[mm], bfr[nn], acc[mm][nn], 0, 0, 0);
    }
    if (s + 1 < steps) {
      #pragma unroll
      for (int i = 0; i < AU; i++) *(s8v*)&As[buf^1][arow[i]*72 + akseg[i]] = ra[i];
      #pragma unroll
      for (int i = 0; i < 4; i++)  *(s8v*)&Bs[buf^1][brow[i]*72 + bkseg[i]] = rb[i];
    }
    __syncthreads();
  }

  unsigned short* cs = &As[0][0];
  #pragma unroll
  for (int mm = 0; mm < MF; mm++) {
    #pragma unroll
    for (int nn = 0; nn < 4; nn++) {
      const int col = wn*64 + nn*16 + fr;
      const int gcol = n0 + col;
      const int row0 = wm*(BM/2) + mm*16 + (lane >> 4)*4;
      const float bc = g.bias ? g.bias[gcol] : 0.f;
      #pragma unroll
      for (int q = 0; q < 4; q++) {
        const int r = m0 + row0 + q;
        float v = acc[mm][nn][q] + bc;
        if (g.act == 1) v = fmaxf(v, 0.f);
        else if (g.act == 2) v = tanhf(v);
        if (g.res && r < M) v += b2f(g.res[(size_t)r*512 + gcol]);
        cs[(row0 + q)*136 + col] = f2b(v);
      }
    }
  }
  __syncthreads();
  for (int ch = tid; ch < BM*16; ch += 256) {
    const int row = ch >> 4, c8 = ch & 15;
    const int r = m0 + row;
    if (r < M)
      *(s8v*)(g.C + (size_t)r*512 + n0 + c8*8) = *(const s8v*)&cs[row*136 + c8*8];
  }
}

// ---- 256x256 tile, 512 thr, 8 waves (2m x 4n); for NVP GEMMs ----
__global__ __launch_bounds__(512)
void gemm256(GZ g0, GZ g1, int M, int Kp)
{
  __shared__ __align__(16) unsigned short As[2][256 * 72];
  __shared__ __align__(16) unsigned short Bs[2][256 * 72];
  GZ g = (blockIdx.z == 0) ? g0 : g1;
  const int tid = threadIdx.x;
  const int lane = tid & 63;
  const int wid = tid >> 6;
  const int wm = wid >> 2, wn = wid & 3;       // 2m x 4n
  const int m0 = blockIdx.y * 256, n0 = blockIdx.x * 256;
  const int fr = lane & 15, fko = (lane >> 4) * 8;

  f4v acc[8][4];
  #pragma unroll
  for (int i = 0; i < 8; i++)
    #pragma unroll
    for (int j = 0; j < 4; j++) acc[i][j] = (f4v){0.f, 0.f, 0.f, 0.f};

  const int steps = Kp >> 6;
  s8v ra[4], rb[4];
  const s8v zed = (s8v){0,0,0,0,0,0,0,0};

  int arow[4], akseg[4];
  #pragma unroll
  for (int i = 0; i < 4; i++) { int gx = tid*4 + i; arow[i] = gx >> 3; akseg[i] = (gx & 7) * 8; }

  #pragma unroll
  for (int i = 0; i < 4; i++)
    ra[i] = (m0 + arow[i] < M) ? *(const s8v*)(g.A + (size_t)(m0 + arow[i])*Kp + akseg[i]) : zed;
  #pragma unroll
  for (int i = 0; i < 4; i++)
    rb[i] = *(const s8v*)(g.B + (size_t)(n0 + arow[i])*Kp + akseg[i]);
  #pragma unroll
  for (int i = 0; i < 4; i++) *(s8v*)&As[0][arow[i]*72 + akseg[i]] = ra[i];
  #pragma unroll
  for (int i = 0; i < 4; i++) *(s8v*)&Bs[0][arow[i]*72 + akseg[i]] = rb[i];
  __syncthreads();

  for (int s = 0; s < steps; s++) {
    if (s + 1 < steps) {
      const int ko = (s + 1) * 64;
      #pragma unroll
      for (int i = 0; i < 4; i++)
        ra[i] = (m0 + arow[i] < M) ? *(const s8v*)(g.A + (size_t)(m0 + arow[i])*Kp + ko + akseg[i]) : zed;
      #pragma unroll
      for (int i = 0; i < 4; i++)
        rb[i] = *(const s8v*)(g.B + (size_t)(n0 + arow[i])*Kp + ko + akseg[i]);
    }
    const int buf = s & 1;
    #pragma unroll
    for (int kk = 0; kk < 2; kk++) {
      s8v af[8], bfr[4];
      #pragma unroll
      for (int mm = 0; mm < 8; mm++)
        af[mm] = *(const s8v*)&As[buf][(wm*128 + mm*16 + fr)*72 + kk*32 + fko];
      #pragma unroll
      for (int nn = 0; nn < 4; nn++)
        bfr[nn] = *(const s8v*)&Bs[buf][(wn*64 + nn*16 + fr)*72 + kk*32 + fko];
      #pragma unroll
      for (int mm = 0; mm < 8; mm++)
        #pragma unroll
        for (int nn = 0; nn < 4; nn++)
          acc[mm][nn] = __builtin_amdgcn_mfma_f32_16x16x32_bf16(af[mm], bfr[nn], acc[mm][nn], 0, 0, 0);
    }
    if (s + 1 < steps) {
      #pragma unroll
      for (int i = 0; i < 4; i++) *(s8v*)&As[buf^1][arow[i]*72 + akseg[i]] = ra[i];
      #pragma unroll
      for (int i = 0; i < 4; i++) *(s8v*)&Bs[buf^1][arow[i]*72 + akseg[i]] = rb[i];
    }
    __syncthreads();
  }

  // staged epilogue: [256][264] bf16 spans As+Bs (135168 B <= 147456 B)
  unsigned short* cs = &As[0][0];
  #pragma unroll
  for (int mm = 0; mm < 8; mm++) {
    #pragma unroll
    for (int nn = 0; nn < 4; nn++) {
      const int col = wn*64 + nn*16 + fr;
      const int gcol = n0 + col;
      const int row0 = wm*128 + mm*16 + (lane >> 4)*4;
      const float bc = g.bias ? g.bias[gcol] : 0.f;
      #pragma unroll
      for (int q = 0; q < 4; q++) {
        const int r = m0 + row0 + q;
        float v = acc[mm][nn][q] + bc;
        if (g.act == 1) v = fmaxf(v, 0.f);
        else if (g.act == 2) v = tanhf(v);
        if (g.res && r < M) v += b2f(g.res[(size_t)r*512 + gcol]);
        cs[(row0 + q)*264 + col] = f2b(v);
      }
    }
  }
  __syncthreads();
  for (int ch = tid; ch < 256*32; ch += 512) {
    const int row = ch >> 5, c8 = ch & 31;
    const int r = m0 + row;
    if (r < M)
      *(s8v*)(g.C + (size_t)r*512 + n0 + c8*8) = *(const s8v*)&cs[row*264 + c8*8];
  }
}

// ============================================================
// KV projection GEMM
// ============================================================
__global__ __launch_bounds__(512)
void gemm_kv(const unsigned short* __restrict__ A, const unsigned short* __restrict__ B,
             const float* __restrict__ kb, const float* __restrict__ vb,
             unsigned short* __restrict__ C, int M)
{
  __shared__ __align__(16) unsigned short Al[128*456];
  __shared__ __align__(16) unsigned short Bst[2][128*72];
  const int tid = threadIdx.x;
  const int lane = tid & 63, wid = tid >> 6;
  const int wm = wid >> 1, wn = wid & 1;
  const int m0 = blockIdx.x * 128;
  const int fr = lane & 15, fko = (lane >> 4) * 8;
  const s8v zed = (s8v){0,0,0,0,0,0,0,0};

  #pragma unroll
  for (int i = 0; i < 14; i++) {
    const int idx = tid + i*512;
    const int row = idx / 56, c8 = idx - row*56;
    const s8v v = (m0 + row < M) ? *(const s8v*)(A + (size_t)(m0 + row)*448 + c8*8) : zed;
    *(s8v*)&Al[row*456 + c8*8] = v;
  }

  int brow[2], bkseg[2];
  #pragma unroll
  for (int i = 0; i < 2; i++) { const int gx = tid*2 + i; brow[i] = gx >> 3; bkseg[i] = (gx & 7)*8; }

  for (int ns = 0; ns < 8; ns++) {
    const unsigned short* Bn = B + (size_t)ns*128*448;
    s8v rb[2];
    #pragma unroll
    for (int i = 0; i < 2; i++)
      rb[i] = *(const s8v*)(Bn + (size_t)brow[i]*448 + bkseg[i]);
    #pragma unroll
    for (int i = 0; i < 2; i++) *(s8v*)&Bst[0][brow[i]*72 + bkseg[i]] = rb[i];
    __syncthreads();

    f4v acc[2][4];
    #pragma unroll
    for (int i = 0; i < 2; i++)
      #pragma unroll
      for (int j = 0; j < 4; j++) acc[i][j] = (f4v){0.f, 0.f, 0.f, 0.f};

    for (int s = 0; s < 7; s++) {
      if (s + 1 < 7) {
        const int ko = (s + 1)*64;
        #pragma unroll
        for (int i = 0; i < 2; i++)
          rb[i] = *(const s8v*)(Bn + (size_t)brow[i]*448 + ko + bkseg[i]);
      }
      const int buf = s & 1;
      #pragma unroll
      for (int kk = 0; kk < 2; kk++) {
        s8v af[2], bfr[4];
        #pragma unroll
        for (int mm = 0; mm < 2; mm++)
          af[mm] = *(const s8v*)&Al[(wm*32 + mm*16 + fr)*456 + s*64 + kk*32 + fko];
        #pragma unroll
        for (int nn = 0; nn < 4; nn++)
          bfr[nn] = *(const s8v*)&Bst[buf][(wn*64 + nn*16 + fr)*72 + kk*32 + fko];
        #pragma unroll
        for (int mm = 0; mm < 2; mm++)
          #pragma unroll
          for (int nn = 0; nn < 4; nn++)
            acc[mm][nn] = __builtin_amdgcn_mfma_f32_16x16x32_bf16(af[mm], bfr[nn], acc[mm][nn], 0, 0, 0);
      }
      if (s + 1 < 7) {
        #pragma unroll
        for (int i = 0; i < 2; i++) *(s8v*)&Bst[buf^1][brow[i]*72 + bkseg[i]] = rb[i];
      }
      __syncthreads();
    }

    unsigned short* cs = &Bst[0][0];
    #pragma unroll
    for (int mm = 0; mm < 2; mm++) {
      #pragma unroll
      for (int nn = 0; nn < 4; nn++) {
        const int col = wn*64 + nn*16 + fr;
        const int cg = ns*128 + col;
        const int row0 = wm*32 + mm*16 + (lane >> 4)*4;
        const float bc = (cg < 512) ? kb[cg] : vb[cg - 512];
        #pragma unroll
        for (int q = 0; q < 4; q++)
          cs[(row0 + q)*136 + col] = f2b(acc[mm][nn][q] + bc);
      }
    }
    __syncthreads();
    #pragma unroll
    for (int i = 0; i < 4; i++) {
      const int ch = tid + i*512;
      const int row = ch >> 4, c8 = ch & 15;
      const int r = m0 + row;
      if (r < M)
        *(s8v*)(C + (size_t)r*1024 + ns*128 + c8*8) = *(const s8v*)&cs[row*136 + c8*8];
    }
    __syncthreads();
  }
}

// ============================================================
// Prep kernels
// ============================================================
__global__ void prep_evb(const float* __restrict__ enc, const float* __restrict__ tv,
                         unsigned short* __restrict__ evb)
{
  const int r = blockIdx.x;
  const int bn = r / 48, t = r - bn * 48;
  for (int col = threadIdx.x; col < 448; col += 256) {
    unsigned short o = 0;
    if (col < 387) {
      const int v = col / 129, cc = col - v * 129;
      const float val = (cc < 128) ? enc[(((size_t)bn*3 + v)*48 + t)*128 + cc]
                                   : tv[((size_t)bn*3 + v)*48 + t];
      o = f2b(val);
    }
    evb[(size_t)r*448 + col] = o;
  }
}

__global__ void prep_attb(const float* __restrict__ enc, unsigned short* __restrict__ attb)
{
  const int r = blockIdx.x;
  const int bn = r / 12, q = r - bn * 12;
  for (int col = threadIdx.x; col < 384; col += 256) {
    const int v = col >> 7, cc = col & 127;
    attb[(size_t)r*384 + col] = f2b(enc[(((size_t)bn*3 + v)*48 + 36 + q)*128 + cc]);
  }
}

__global__ void prep_wkv(const float* __restrict__ Wk, const float* __restrict__ Wv,
                         unsigned short* __restrict__ WT)
{
  const int l = blockIdx.y, n = blockIdx.x;
  const int kvs = n >> 9, h = (n >> 6) & 7, d = n & 63;
  const float* src = (kvs ? Wv : Wk) + ((size_t)(l*8 + h)*387)*64 + d;
  unsigned short* dst = WT + ((size_t)l*1024 + n)*448;
  for (int k = threadIdx.x; k < 448; k += 256)
    dst[k] = (k < 387) ? f2b(src[(size_t)k*64]) : 0;
}

__global__ void prep_wsh(const float* __restrict__ W, unsigned short* __restrict__ WT)
{
  const int n = blockIdx.x;
  for (int k = threadIdx.x; k < 384; k += 256)
    WT[(size_t)n*384 + k] = f2b(W[(size_t)k*512 + n]);
}

__global__ void prep_wff(const float* __restrict__ W1, const float* __restrict__ W2,
                         unsigned short* __restrict__ T1, unsigned short* __restrict__ T2b)
{
  const int n = blockIdx.x, l = blockIdx.y, which = blockIdx.z;
  const float* src = (which ? W2 : W1) + (size_t)l*512*512;
  unsigned short* dst = (which ? T2b : T1) + ((size_t)l*512 + n)*512;
  for (int k = threadIdx.x; k < 512; k += 256)
    dst[k] = f2b(src[(size_t)k*512 + n]);
}

__global__ void prep_wnvp_in(const float* __restrict__ Ws, const float* __restrict__ Wt,
                             unsigned short* __restrict__ Ts, unsigned short* __restrict__ Tt)
{
  const int n = blockIdx.x, blk = blockIdx.y, net = blockIdx.z;
  const float* src = (net ? Wt : Ws) + (size_t)blk*515*512;
  unsigned short* dst = (net ? Tt : Ts) + ((size_t)blk*512 + n)*576;
  for (int k = threadIdx.x; k < 576; k += 256)
    dst[k] = (k < 515) ? f2b(src[(size_t)k*512 + n]) : 0;
}

__global__ void prep_wnvp_hid(const float* __restrict__ Ws, const float* __restrict__ Wt,
                              unsigned short* __restrict__ Ts, unsigned short* __restrict__ Tt)
{
  const int n = blockIdx.x, bi = blockIdx.y, net = blockIdx.z;
  const float* src = (net ? Wt : Ws) + (size_t)bi*512*512;
  unsigned short* dst = (net ? Tt : Ts) + ((size_t)bi*512 + n)*512;
  for (int k = threadIdx.x; k < 512; k += 256)
    dst[k] = f2b(src[(size_t)k*512 + n]);
}

__global__ void pad_ab_kernel(unsigned short* __restrict__ ab)
{
  const int r = blockIdx.x;
  if (threadIdx.x < 64) ab[(size_t)r*576 + 512 + threadIdx.x] = 0;
}

__global__ void zero_stats_kernel(float* __restrict__ sraw)
{
  const int i = blockIdx.x * blockDim.x + threadIdx.x;
  if (i < 6*36*2) sraw[i] = 0.f;
}

// ============================================================
// Attention + LN1: 650 blocks x 512 thr; wave h owns head h.
// LDS diet: av/att staged bf16 (77 KB total -> 2 blocks/CU).
// ============================================================
__global__ __launch_bounds__(512)
void attn_kernel(const unsigned short* __restrict__ avb, const unsigned short* __restrict__ kvb,
                 const float* __restrict__ lns, const float* __restrict__ lnb,
                 unsigned short* __restrict__ av2b)
{
  const int b = blockIdx.x, tid = threadIdx.x;
  const int h = tid >> 6, lane = tid & 63;
  __shared__ unsigned short avs [12][520];
  __shared__ unsigned short atts[12][520];
  __shared__ unsigned short vsh[8][48][68];

  // cooperative copy av rows (bf16, no conversion)
  for (int idx = tid; idx < 12*64; idx += 512) {
    const int v = idx >> 6, c8 = idx & 63;
    *(s8v*)&avs[v][c8*8] = *(const s8v*)(avb + (((size_t)b*12 + v) << 9) + c8*8);
  }
  // per-wave: V tile for head h
  {
    const int t0 = lane >> 3, c8 = lane & 7;
    #pragma unroll
    for (int i = 0; i < 6; i++) {
      const int t = i*8 + t0;
      *(s8v*)&vsh[h][t][c8*8] =
          *(const s8v*)(kvb + (size_t)(b*48 + t)*1024 + 512 + h*64 + c8*8);
    }
  }
  __syncthreads();

  const int tcl = (lane < 48) ? lane : 0;
  s8v kp[8];
  {
    const unsigned short* kr = kvb + (size_t)(b*48 + tcl)*1024 + h*64;
    #pragma unroll
    for (int i = 0; i < 8; i++) kp[i] = *(const s8v*)(kr + i*8);
  }

  // ---- scores ----
  float p[12];
  #pragma unroll
  for (int v = 0; v < 12; v++) p[v] = 0.f;
  #pragma unroll
  for (int k8 = 0; k8 < 8; k8++) {
    float kf[8];
    #pragma unroll
    for (int j = 0; j < 8; j++) kf[j] = b2f((unsigned short)kp[k8][j]);
    #pragma unroll
    for (int v = 0; v < 12; v++) {
      const s8v q8 = *(const s8v*)&avs[v][h*64 + k8*8];
      #pragma unroll
      for (int j = 0; j < 8; j++) p[v] = fmaf(b2f((unsigned short)q8[j]), kf[j], p[v]);
    }
  }
  // ---- softmax over keys ----
  #pragma unroll
  for (int v = 0; v < 12; v++) {
    const bool valid = (lane < 36 + v);
    float s = valid ? p[v]*0.125f : -1e30f;
    float m = s;
    #pragma unroll
    for (int off = 1; off < 64; off <<= 1) m = fmaxf(m, __shfl_xor(m, off));
    const float e = valid ? expf(s - m) : 0.f;
    float sum = e;
    #pragma unroll
    for (int off = 1; off < 64; off <<= 1) sum += __shfl_xor(sum, off);
    p[v] = e / sum;
  }
  // ---- PV ----
  float o[12];
  #pragma unroll
  for (int v = 0; v < 12; v++) o[v] = 0.f;
  #pragma unroll
  for (int t6 = 0; t6 < 6; t6++) {
    float vf[8];
    #pragma unroll
    for (int j = 0; j < 8; j++) vf[j] = b2f(vsh[h][t6*8 + j][lane]);
    #pragma unroll
    for (int j = 0; j < 8; j++) {
      const int tt = t6*8 + j;
      #pragma unroll
      for (int v = 0; v < 12; v++) o[v] = fmaf(__shfl(p[v], tt), vf[j], o[v]);
    }
  }
  #pragma unroll
  for (int v = 0; v < 12; v++) atts[v][h*64 + lane] = f2b(o[v]);
  __syncthreads();

  // ---- LN1 ----
  for (int v = h; v < 12; v += 8) {
    float x[8], sm = 0.f, s2 = 0.f;
    const s8v a8 = *(const s8v*)&avs[v][lane*8];
    const s8v t8 = *(const s8v*)&atts[v][lane*8];
    #pragma unroll
    for (int j = 0; j < 8; j++) {
      const float t = b2f((unsigned short)a8[j]) + b2f((unsigned short)t8[j]);
      x[j] = t; sm += t; s2 += t*t;
    }
    #pragma unroll
    for (int off = 32; off; off >>= 1) { sm += __shfl_xor(sm, off); s2 += __shfl_xor(s2, off); }
    const float mean = sm * (1.f/512.f);
    const float var  = s2 * (1.f/512.f) - mean*mean;
    const float rr = rsqrtf(var + 1e-5f);
    #pragma unroll
    for (int j = 0; j < 8; j++) {
      const int c = lane*8 + j;
      av2b[(((size_t)b*12 + v) << 9) + c] = f2b((x[j] - mean)*rr*lns[c] + lnb[c]);
    }
  }
}

// LN over bf16 rows [7800][512] -> out with stride ldo
__global__ __launch_bounds__(256)
void ln_kernel(const unsigned short* __restrict__ in, unsigned short* __restrict__ out, int ldo,
               const float* __restrict__ s, const float* __restrict__ b)
{
  const int row = blockIdx.x*4 + (threadIdx.x >> 6);
  const int lane = threadIdx.x & 63;
  const s8v xv = *(const s8v*)(in + (size_t)row*512 + lane*8);
  float x[8], sm = 0.f, s2 = 0.f;
  #pragma unroll
  for (int j = 0; j < 8; j++) {
    const float t = b2f((unsigned short)xv[j]);
    x[j] = t; sm += t; s2 += t*t;
  }
  #pragma unroll
  for (int o = 32; o; o >>= 1) { sm += __shfl_xor(sm, o); s2 += __shfl_xor(s2, o); }
  const float mean = sm * (1.f/512.f);
  const float var  = s2 * (1.f/512.f) - mean*mean;
  const float rr = rsqrtf(var + 1e-5f);
  s8v o8;
  #pragma unroll
  for (int j = 0; j < 8; j++) {
    const int c = lane*8 + j;
    o8[j] = (short)f2b((x[j] - mean)*rr*s[c] + b[c]);
  }
  *(s8v*)(out + (size_t)row*ldo + lane*8) = o8;
}

// ============================================================
// NVP small kernels
// ============================================================
__global__ void mu_kernel(const float* __restrict__ tv, const float* __restrict__ u,
                          const float* __restrict__ sab, float* __restrict__ uinf,
                          unsigned short* __restrict__ ab, int blk)
{
  const int r = blockIdx.x*256 + threadIdx.x;
  if (r >= NROWS_) return;
  const int bn = r / 12, q = r - bn * 12;
  float uv[3];
  #pragma unroll
  for (int v = 0; v < 3; v++) {
    if (blk == 0) uv[v] = tv[((size_t)bn*3 + v)*48 + 36 + q];
    else {
      const float a = sab[((blk-1)*36 + q*3 + v)*2 + 0];
      const float c = sab[((blk-1)*36 + q*3 + v)*2 + 1];
      uv[v] = fmaf(a, u[(size_t)r*3 + v], c);
    }
  }
  #pragma unroll
  for (int v = 0; v < 3; v++) {
    uinf[(size_t)r*3 + v] = uv[v];
    ab[(size_t)r*576 + 512 + v] = f2b(((v + blk) & 1) ? uv[v] : 0.f);
  }
}

__global__ __launch_bounds__(512)
void out_couple_kernel(const unsigned short* __restrict__ hs, const unsigned short* __restrict__ ht,
                const float* __restrict__ swo, const float* __restrict__ sbo,
                const float* __restrict__ two, const float* __restrict__ tbo,
                const float* __restrict__ uinf, float* __restrict__ u, float* __restrict__ ld,
                float* __restrict__ sraw, int blk)
{
  __shared__ float sres[4][2][3];
  const int tid = threadIdx.x;
  const int w = tid >> 6, lane = tid & 63;
  const int rloc = w >> 1, net = w & 1;
  const int r = blockIdx.x*4 + rloc;
  const unsigned short* hrow = (net ? ht : hs) + ((size_t)r << 9);
  const float* wo = (net ? two : swo) + (size_t)blk*512*3;

  const s8v hv8 = *(const s8v*)(hrow + lane*8);
  float wbuf[24];
  #pragma unroll
  for (int i = 0; i < 6; i++)
    *(float4*)&wbuf[i*4] = *(const float4*)(wo + lane*24 + i*4);
  float a0 = 0.f, a1 = 0.f, a2 = 0.f;
  #pragma unroll
  for (int i = 0; i < 8; i++) {
    const float hv = b2f((unsigned short)hv8[i]);
    a0 = fmaf(hv, wbuf[i*3+0], a0);
    a1 = fmaf(hv, wbuf[i*3+1], a1);
    a2 = fmaf(hv, wbuf[i*3+2], a2);
  }
  #pragma unroll
  for (int o = 32; o; o >>= 1) {
    a0 += __shfl_xor(a0, o); a1 += __shfl_xor(a1, o); a2 += __shfl_xor(a2, o);
  }
  if (lane == 0) {
    const float* bo = (net ? tbo : sbo) + blk*3;
    sres[rloc][net][0] = a0 + bo[0];
    sres[rloc][net][1] = a1 + bo[1];
    sres[rloc][net][2] = a2 + bo[2];
  }
  __syncthreads();
  if (tid < 12) {
    const int rl = tid / 3, j = tid - 3*rl;
    const int r2 = blockIdx.x*4 + rl;
    const int q = r2 % 12;
    const int msk = (j + blk) & 1;
    const float s = sres[rl][0][j];
    const float t = sres[rl][1][j];
    const float uo = uinf[(size_t)r2*3 + j];
    const float unew = msk ? uo : (uo - t) * expf(-s);
    u[(size_t)r2*3 + j] = unew;
    const float prev = blk ? ld[(size_t)r2*3 + j] : 0.f;
    ld[(size_t)r2*3 + j] = prev - (msk ? 0.f : s);
    atomicAdd(&sraw[(blk*36 + q*3 + j)*2 + 0], unew);
    atomicAdd(&sraw[(blk*36 + q*3 + j)*2 + 1], unew * unew);
  }
}

__global__ void bn_finalize_kernel(const float* __restrict__ sraw, float* __restrict__ sab,
    float* __restrict__ ldadd, const float* __restrict__ lg, const float* __restrict__ bt, int blk)
{
  const int idx = threadIdx.x;
  if (idx < 36) {
    const int v = idx % 3;
    const float sum = sraw[(blk*36 + idx)*2 + 0];
    const float s2  = sraw[(blk*36 + idx)*2 + 1];
    const float bm  = sum * (1.f / 650.f);
    const float bvr = s2 * (1.f / 650.f) - bm * bm;
    const float g = lg[blk*3 + v];
    const float a = expf(g) * rsqrtf(bvr + 1e-5f);
    sab[(blk*36 + idx)*2 + 0] = a;
    sab[(blk*36 + idx)*2 + 1] = bt[blk*3 + v] - a * bm;
    ldadd[blk*36 + idx] = g - 0.5f * logf(bvr + 1e-5f);
  }
}

__global__ void loss_kernel(const float* __restrict__ u, const float* __restrict__ ld,
    const float* __restrict__ sab, const float* __restrict__ ldadd, float* __restrict__ out)
{
  const int bn = blockIdx.x * blockDim.x + threadIdx.x;
  if (bn >= BN_) return;
  float acc = 0.f;
  for (int t2 = 0; t2 < 12; t2++) {
    #pragma unroll
    for (int v = 0; v < 3; v++) {
      const int idx = t2*3 + v;
      const float a = sab[(5*36 + idx)*2 + 0];
      const float c = sab[(5*36 + idx)*2 + 1];
      const float ur = u[((size_t)bn*12 + t2)*3 + v];
      const float ub = fmaf(a, ur, c);
      acc += 0.5f*ub*ub + 0.5f*LOG2PI_ - ld[((size_t)bn*12 + t2)*3 + v];
    }
  }
  float lsum = 0.f;
  for (int i = 0; i < 6*36; i++) lsum += ldadd[i];
  out[bn] = acc - lsum;
}

// ============================================================
// workspace byte offsets
// ============================================================
#define O_WKV    (size_t)0
#define O_WSH    (size_t)3670016
#define O_WFF1   (size_t)4063232
#define O_WFF2   (size_t)6160384
#define O_WSIN   (size_t)8257536
#define O_WTIN   (size_t)11796480
#define O_WSHID  (size_t)15335424
#define O_WTHID  (size_t)27918336
#define O_EVB    (size_t)40501248
#define O_ATTB   (size_t)68456448
#define O_AVB    (size_t)74446848
#define O_AV2B   (size_t)82434048
#define O_HB     (size_t)90421248
#define O_FFSUM  (size_t)98408448
#define O_KVB    (size_t)106395648
#define O_AB     O_KVB
#define O_HS0    (O_KVB + 8985600)
#define O_HS1    (O_HS0 + 7987200)
#define O_HT0    (O_HS1 + 7987200)
#define O_HT1    (O_HT0 + 7987200)
#define O_UINF   (size_t)170293248
#define O_U      (size_t)170386848
#define O_LD     (size_t)170480448
#define O_SRAW   (size_t)170761248
#define O_SAB    (size_t)170762976
#define O_LDA    (size_t)170764704

static inline GZ mkgz(const void* A, const void* B, const float* bias, void* C,
                      const void* res, int act) {
  GZ g; g.A = (const unsigned short*)A; g.B = (const unsigned short*)B; g.bias = bias;
  g.C = (unsigned short*)C; g.res = (const unsigned short*)res; g.act = act; return g;
}

extern "C" void kernel_launch(void* const* d_in, const int* in_sizes, int n_in,
                              void* d_out, int out_size, void* d_ws, size_t ws_size,
                              hipStream_t stream)
{
  const float* enc   = (const float*)d_in[0];
  const float* tv    = (const float*)d_in[1];
  const float* Wsh   = (const float*)d_in[2];
  const float* bsh   = (const float*)d_in[3];
  const float* Wk    = (const float*)d_in[4];
  const float* bk    = (const float*)d_in[5];
  const float* Wv    = (const float*)d_in[6];
  const float* bv    = (const float*)d_in[7];
  const float* ln1s  = (const float*)d_in[8];
  const float* ln1b  = (const float*)d_in[9];
  const float* fw1   = (const float*)d_in[10];
  const float* fb1   = (const float*)d_in[11];
  const float* fw2   = (const float*)d_in[12];
  const float* fb2   = (const float*)d_in[13];
  const float* ln2s  = (const float*)d_in[14];
  const float* ln2b  = (const float*)d_in[15];
  const float* swin  = (const float*)d_in[16];
  const float* sbin  = (const float*)d_in[17];
  const float* swhid = (const float*)d_in[18];
  const float* sbhid = (const float*)d_in[19];
  const float* swout = (const float*)d_in[20];
  const float* sbout = (const float*)d_in[21];
  const float* twin  = (const float*)d_in[22];
  const float* tbin  = (const float*)d_in[23];
  const float* twhid = (const float*)d_in[24];
  const float* tbhid = (const float*)d_in[25];
  const float* twout = (const float*)d_in[26];
  const float* tbout = (const float*)d_in[27];
  const float* bnlg  = (const float*)d_in[28];
  const float* bnbt  = (const float*)d_in[29];

  char* ws = (char*)d_ws;
  unsigned short* wkv   = (unsigned short*)(ws + O_WKV);
  unsigned short* wsht  = (unsigned short*)(ws + O_WSH);
  unsigned short* wff1t = (unsigned short*)(ws + O_WFF1);
  unsigned short* wff2t = (unsigned short*)(ws + O_WFF2);
  unsigned short* wsint = (unsigned short*)(ws + O_WSIN);
  unsigned short* wtint = (unsigned short*)(ws + O_WTIN);
  unsigned short* wshid = (unsigned short*)(ws + O_WSHID);
  unsigned short* wthid = (unsigned short*)(ws + O_WTHID);
  unsigned short* evb   = (unsigned short*)(ws + O_EVB);
  unsigned short* attb  = (unsigned short*)(ws + O_ATTB);
  unsigned short* avb   = (unsigned short*)(ws + O_AVB);
  unsigned short* av2b  = (unsigned short*)(ws + O_AV2B);
  unsigned short* hb    = (unsigned short*)(ws + O_HB);
  unsigned short* ffsum = (unsigned short*)(ws + O_FFSUM);
  unsigned short* kvb   = (unsigned short*)(ws + O_KVB);
  unsigned short* ab    = (unsigned short*)(ws + O_AB);
  unsigned short* hs0   = (unsigned short*)(ws + O_HS0);
  unsigned short* hs1   = (unsigned short*)(ws + O_HS1);
  unsigned short* ht0   = (unsigned short*)(ws + O_HT0);
  unsigned short* ht1   = (unsigned short*)(ws + O_HT1);
  float* uinf  = (float*)(ws + O_UINF);
  float* u     = (float*)(ws + O_U);
  float* ld    = (float*)(ws + O_LD);
  float* sraw  = (float*)(ws + O_SRAW);
  float* sab   = (float*)(ws + O_SAB);
  float* lda   = (float*)(ws + O_LDA);
  float* out   = (float*)d_out;

  // ---- prep ----
  prep_evb<<<MKV_, 256, 0, stream>>>(enc, tv, evb);
  prep_attb<<<NROWS_, 256, 0, stream>>>(enc, attb);
  prep_wkv<<<dim3(1024, 4), 256, 0, stream>>>(Wk, Wv, wkv);
  prep_wsh<<<512, 256, 0, stream>>>(Wsh, wsht);
  prep_wff<<<dim3(512, 4, 2), 256, 0, stream>>>(fw1, fw2, wff1t, wff2t);
  prep_wnvp_in<<<dim3(512, 6, 2), 256, 0, stream>>>(swin, twin, wsint, wtint);
  prep_wnvp_hid<<<dim3(512, 24, 2), 256, 0, stream>>>(swhid, twhid, wshid, wthid);
  zero_stats_kernel<<<2, 256, 0, stream>>>(sraw);

  const GZ gnull = mkgz(nullptr, nullptr, nullptr, nullptr, nullptr, 0);

  // ---- shift GEMM ----
  {
    GZ g = mkgz(attb, wsht, bsh, avb, nullptr, 0);
    gemm_bf16<128><<<dim3(4, 61, 1), 256, 0, stream>>>(g, gnull, NROWS_, 384);
  }

  // ---- transformer layers ----
  for (int l = 0; l < 4; l++) {
    gemm_kv<<<244, 512, 0, stream>>>(evb, wkv + (size_t)l*1024*448,
        bk + l*512, bv + l*512, kvb, MKV_);
    attn_kernel<<<BN_, 512, 0, stream>>>(avb, kvb, ln1s + l*512, ln1b + l*512, av2b);
    GZ g1 = mkgz(av2b, wff1t + (size_t)l*512*512, fb1 + l*512, hb, nullptr, 1);
    gemm_bf16<128><<<dim3(4, 61, 1), 256, 0, stream>>>(g1, gnull, NROWS_, 512);
    GZ g2 = mkgz(hb, wff2t + (size_t)l*512*512, fb2 + l*512, ffsum, av2b, 0);
    gemm_bf16<128><<<dim3(4, 61, 1), 256, 0, stream>>>(g2, gnull, NROWS_, 512);
    if (l == 3)
      ln_kernel<<<1950, 256, 0, stream>>>(ffsum, ab, 576, ln2s + l*512, ln2b + l*512);
    else
      ln_kernel<<<1950, 256, 0, stream>>>(ffsum, avb, 512, ln2s + l*512, ln2b + l*512);
  }

  // ---- RealNVP (256x256 tiles) ----
  pad_ab_kernel<<<NROWS_, 64, 0, stream>>>(ab);
  for (int blk = 0; blk < 6; blk++) {
    mu_kernel<<<31, 256, 0, stream>>>(tv, u, sab, uinf, ab, blk);
    {
      GZ gs = mkgz(ab, wsint + (size_t)blk*512*576, sbin + blk*512, hs0, nullptr, 2);
      GZ gt = mkgz(ab, wtint + (size_t)blk*512*576, tbin + blk*512, ht0, nullptr, 1);
      gemm256<<<dim3(2, 31, 2), 512, 0, stream>>>(gs, gt, NROWS_, 576);
    }
    for (int i = 0; i < 4; i++) {
      unsigned short* srcs = (i & 1) ? hs1 : hs0;
      unsigned short* dsts = (i & 1) ? hs0 : hs1;
      unsigned short* srct = (i & 1) ? ht1 : ht0;
      unsigned short* dstt = (i & 1) ? ht0 : ht1;
      GZ gs = mkgz(srcs, wshid + (size_t)(blk*4 + i)*512*512, sbhid + (blk*4 + i)*512, dsts, nullptr, 2);
      GZ gt = mkgz(srct, wthid + (size_t)(blk*4 + i)*512*512, tbhid + (blk*4 + i)*512, dstt, nullptr, 1);
      gemm256<<<dim3(2, 31, 2), 512, 0, stream>>>(gs, gt, NROWS_, 512);
    }
    out_couple_kernel<<<1950, 512, 0, stream>>>(hs0, ht0, swout, sbout, twout, tbout,
        uinf, u, ld, sraw, blk);
    bn_finalize_kernel<<<1, 64, 0, stream>>>(sraw, sab, lda, bnlg, bnbt, blk);
  }
  loss_kernel<<<3, 256, 0, stream>>>(u, ld, sab, lda, out);
}

// Round 11
// 2074.764 us; speedup vs baseline: 1.3538x; 1.3538x over previous
//
#include <hip/hip_runtime.h>
#include <math.h>

// ---- problem dims ----
#define BN_ 650
#define T_ 48
#define V_ 3
#define T2_ 12
#define NROWS_ 7800            // BN_*T2_
#define MKV_ 31200             // BN_*T_
#define LOG2PI_ 1.8378770664093453f

typedef short s8v __attribute__((ext_vector_type(8)));
typedef float f4v __attribute__((ext_vector_type(4)));

__device__ __forceinline__ float b2f(unsigned short h) {
  return __uint_as_float(((unsigned)h) << 16);
}
__device__ __forceinline__ unsigned short f2b(float f) {
  unsigned u = __float_as_uint(f);
  return (unsigned short)((u + 0x7fffu + ((u >> 16) & 1u)) >> 16);
}

// ============================================================
// bf16 MFMA GEMM: C[M,512] = act(A[M,Kp] @ BT[512,Kp]^T + bias)(+res)
// BT pre-transposed [N][Kp] bf16. 128x128 tile, 256 thr, 4 waves (2x2).
// ============================================================
struct GZ {
  const unsigned short* A;
  const unsigned short* B;
  const float* bias;
  unsigned short* C;
  const unsigned short* res;
  int act;   // 0 none, 1 relu, 2 tanh
};

template<int BM>
__global__ __launch_bounds__(256)
void gemm_bf16(GZ g0, GZ g1, int M, int Kp)
{
  constexpr int MF = BM / 32;
  constexpr int AU = BM / 32;
  __shared__ __align__(16) unsigned short As[2][BM * 72];
  __shared__ __align__(16) unsigned short Bs[2][128 * 72];
  GZ g = (blockIdx.z == 0) ? g0 : g1;
  const int tid = threadIdx.x;
  const int lane = tid & 63;
  const int wid = tid >> 6;
  const int wm = wid >> 1, wn = wid & 1;
  const int m0 = blockIdx.y * BM, n0 = blockIdx.x * 128;
  const int fr = lane & 15, fko = (lane >> 4) * 8;

  f4v acc[MF][4];
  #pragma unroll
  for (int i = 0; i < MF; i++)
    #pragma unroll
    for (int j = 0; j < 4; j++) acc[i][j] = (f4v){0.f, 0.f, 0.f, 0.f};

  const int steps = Kp >> 6;
  s8v ra[AU], rb[4];
  const s8v zed = (s8v){0,0,0,0,0,0,0,0};

  int arow[AU], akseg[AU], brow[4], bkseg[4];
  #pragma unroll
  for (int i = 0; i < AU; i++) { int gx = tid*AU + i; arow[i] = gx >> 3; akseg[i] = (gx & 7) * 8; }
  #pragma unroll
  for (int i = 0; i < 4; i++) { int gx = tid*4 + i; brow[i] = gx >> 3; bkseg[i] = (gx & 7) * 8; }

  #pragma unroll
  for (int i = 0; i < AU; i++)
    ra[i] = (m0 + arow[i] < M) ? *(const s8v*)(g.A + (size_t)(m0 + arow[i])*Kp + akseg[i]) : zed;
  #pragma unroll
  for (int i = 0; i < 4; i++)
    rb[i] = *(const s8v*)(g.B + (size_t)(n0 + brow[i])*Kp + bkseg[i]);
  #pragma unroll
  for (int i = 0; i < AU; i++) *(s8v*)&As[0][arow[i]*72 + akseg[i]] = ra[i];
  #pragma unroll
  for (int i = 0; i < 4; i++)  *(s8v*)&Bs[0][brow[i]*72 + bkseg[i]] = rb[i];
  __syncthreads();

  for (int s = 0; s < steps; s++) {
    if (s + 1 < steps) {
      const int ko = (s + 1) * 64;
      #pragma unroll
      for (int i = 0; i < AU; i++)
        ra[i] = (m0 + arow[i] < M) ? *(const s8v*)(g.A + (size_t)(m0 + arow[i])*Kp + ko + akseg[i]) : zed;
      #pragma unroll
      for (int i = 0; i < 4; i++)
        rb[i] = *(const s8v*)(g.B + (size_t)(n0 + brow[i])*Kp + ko + bkseg[i]);
    }
    const int buf = s & 1;
    #pragma unroll
    for (int kk = 0; kk < 2; kk++) {
      s8v af[MF], bfr[4];
      #pragma unroll
      for (int mm = 0; mm < MF; mm++)
        af[mm] = *(const s8v*)&As[buf][(wm*(BM/2) + mm*16 + fr)*72 + kk*32 + fko];
      #pragma unroll
      for (int nn = 0; nn < 4; nn++)
        bfr[nn] = *(const s8v*)&Bs[buf][(wn*64 + nn*16 + fr)*72 + kk*32 + fko];
      #pragma unroll
      for (int mm = 0; mm < MF; mm++)
        #pragma unroll
        for (int nn = 0; nn < 4; nn++)
          acc[mm][nn] = __builtin_amdgcn_mfma_f32_16x16x32_bf16(af[mm], bfr[nn], acc[mm][nn], 0, 0, 0);
    }
    if (s + 1 < steps) {
      #pragma unroll
      for (int i = 0; i < AU; i++) *(s8v*)&As[buf^1][arow[i]*72 + akseg[i]] = ra[i];
      #pragma unroll
      for (int i = 0; i < 4; i++)  *(s8v*)&Bs[buf^1][brow[i]*72 + bkseg[i]] = rb[i];
    }
    __syncthreads();
  }

  unsigned short* cs = &As[0][0];
  #pragma unroll
  for (int mm = 0; mm < MF; mm++) {
    #pragma unroll
    for (int nn = 0; nn < 4; nn++) {
      const int col = wn*64 + nn*16 + fr;
      const int gcol = n0 + col;
      const int row0 = wm*(BM/2) + mm*16 + (lane >> 4)*4;
      const float bc = g.bias ? g.bias[gcol] : 0.f;
      #pragma unroll
      for (int q = 0; q < 4; q++) {
        const int r = m0 + row0 + q;
        float v = acc[mm][nn][q] + bc;
        if (g.act == 1) v = fmaxf(v, 0.f);
        else if (g.act == 2) v = tanhf(v);
        if (g.res && r < M) v += b2f(g.res[(size_t)r*512 + gcol]);
        cs[(row0 + q)*136 + col] = f2b(v);
      }
    }
  }
  __syncthreads();
  for (int ch = tid; ch < BM*16; ch += 256) {
    const int row = ch >> 4, c8 = ch & 15;
    const int r = m0 + row;
    if (r < M)
      *(s8v*)(g.C + (size_t)r*512 + n0 + c8*8) = *(const s8v*)&cs[row*136 + c8*8];
  }
}

// ============================================================
// KV projection GEMM (A-resident, 8 n-slices)
// ============================================================
__global__ __launch_bounds__(512)
void gemm_kv(const unsigned short* __restrict__ A, const unsigned short* __restrict__ B,
             const float* __restrict__ kb, const float* __restrict__ vb,
             unsigned short* __restrict__ C, int M)
{
  __shared__ __align__(16) unsigned short Al[128*456];
  __shared__ __align__(16) unsigned short Bst[2][128*72];
  const int tid = threadIdx.x;
  const int lane = tid & 63, wid = tid >> 6;
  const int wm = wid >> 1, wn = wid & 1;
  const int m0 = blockIdx.x * 128;
  const int fr = lane & 15, fko = (lane >> 4) * 8;
  const s8v zed = (s8v){0,0,0,0,0,0,0,0};

  #pragma unroll
  for (int i = 0; i < 14; i++) {
    const int idx = tid + i*512;
    const int row = idx / 56, c8 = idx - row*56;
    const s8v v = (m0 + row < M) ? *(const s8v*)(A + (size_t)(m0 + row)*448 + c8*8) : zed;
    *(s8v*)&Al[row*456 + c8*8] = v;
  }

  int brow[2], bkseg[2];
  #pragma unroll
  for (int i = 0; i < 2; i++) { const int gx = tid*2 + i; brow[i] = gx >> 3; bkseg[i] = (gx & 7)*8; }

  for (int ns = 0; ns < 8; ns++) {
    const unsigned short* Bn = B + (size_t)ns*128*448;
    s8v rb[2];
    #pragma unroll
    for (int i = 0; i < 2; i++)
      rb[i] = *(const s8v*)(Bn + (size_t)brow[i]*448 + bkseg[i]);
    #pragma unroll
    for (int i = 0; i < 2; i++) *(s8v*)&Bst[0][brow[i]*72 + bkseg[i]] = rb[i];
    __syncthreads();

    f4v acc[2][4];
    #pragma unroll
    for (int i = 0; i < 2; i++)
      #pragma unroll
      for (int j = 0; j < 4; j++) acc[i][j] = (f4v){0.f, 0.f, 0.f, 0.f};

    for (int s = 0; s < 7; s++) {
      if (s + 1 < 7) {
        const int ko = (s + 1)*64;
        #pragma unroll
        for (int i = 0; i < 2; i++)
          rb[i] = *(const s8v*)(Bn + (size_t)brow[i]*448 + ko + bkseg[i]);
      }
      const int buf = s & 1;
      #pragma unroll
      for (int kk = 0; kk < 2; kk++) {
        s8v af[2], bfr[4];
        #pragma unroll
        for (int mm = 0; mm < 2; mm++)
          af[mm] = *(const s8v*)&Al[(wm*32 + mm*16 + fr)*456 + s*64 + kk*32 + fko];
        #pragma unroll
        for (int nn = 0; nn < 4; nn++)
          bfr[nn] = *(const s8v*)&Bst[buf][(wn*64 + nn*16 + fr)*72 + kk*32 + fko];
        #pragma unroll
        for (int mm = 0; mm < 2; mm++)
          #pragma unroll
          for (int nn = 0; nn < 4; nn++)
            acc[mm][nn] = __builtin_amdgcn_mfma_f32_16x16x32_bf16(af[mm], bfr[nn], acc[mm][nn], 0, 0, 0);
      }
      if (s + 1 < 7) {
        #pragma unroll
        for (int i = 0; i < 2; i++) *(s8v*)&Bst[buf^1][brow[i]*72 + bkseg[i]] = rb[i];
      }
      __syncthreads();
    }

    unsigned short* cs = &Bst[0][0];
    #pragma unroll
    for (int mm = 0; mm < 2; mm++) {
      #pragma unroll
      for (int nn = 0; nn < 4; nn++) {
        const int col = wn*64 + nn*16 + fr;
        const int cg = ns*128 + col;
        const int row0 = wm*32 + mm*16 + (lane >> 4)*4;
        const float bc = (cg < 512) ? kb[cg] : vb[cg - 512];
        #pragma unroll
        for (int q = 0; q < 4; q++)
          cs[(row0 + q)*136 + col] = f2b(acc[mm][nn][q] + bc);
      }
    }
    __syncthreads();
    #pragma unroll
    for (int i = 0; i < 4; i++) {
      const int ch = tid + i*512;
      const int row = ch >> 4, c8 = ch & 15;
      const int r = m0 + row;
      if (r < M)
        *(s8v*)(C + (size_t)r*1024 + ns*128 + c8*8) = *(const s8v*)&cs[row*136 + c8*8];
    }
    __syncthreads();
  }
}

// ============================================================
// Coalesced LDS-tiled fp32->bf16 weight transpose.
// src[K][N] fp32 (row-major) -> dst[N][Kp] bf16, zero-fill K..Kp.
// One block = 64(k) x 64(n) tile. grid.x = ktiles*ntiles, grid.y = matrix.
// ============================================================
__global__ __launch_bounds__(256)
void trans_w(const float* __restrict__ src, unsigned short* __restrict__ dst,
             int K, int N, int Kp, int ktiles, size_t sstride, size_t dstride)
{
  __shared__ float tile[64][65];
  const int kt = blockIdx.x % ktiles, nt = blockIdx.x / ktiles;
  const int k0 = kt*64, n0 = nt*64;
  const float* s = src + (size_t)blockIdx.y * sstride;
  unsigned short* d = dst + (size_t)blockIdx.y * dstride;
  const int tid = threadIdx.x;
  const int r = tid >> 4, c4 = (tid & 15) * 4;
  #pragma unroll
  for (int i = 0; i < 4; i++) {
    const int k = k0 + r + i*16;
    float4 v = {0.f, 0.f, 0.f, 0.f};
    if (k < K) v = *(const float4*)(s + (size_t)k*N + n0 + c4);
    tile[r + i*16][c4+0] = v.x; tile[r + i*16][c4+1] = v.y;
    tile[r + i*16][c4+2] = v.z; tile[r + i*16][c4+3] = v.w;
  }
  __syncthreads();
  const int n = tid >> 2, kk0 = (tid & 3) * 16;
  #pragma unroll
  for (int i = 0; i < 2; i++) {
    s8v o;
    #pragma unroll
    for (int j = 0; j < 8; j++)
      o[j] = (short)f2b(tile[kk0 + i*8 + j][n]);
    *(s8v*)(d + (size_t)(n0 + n)*Kp + k0 + kk0 + i*8) = o;
  }
}

// ============================================================
// Prep kernels (activations + KV weights)
// ============================================================
__global__ void prep_evb(const float* __restrict__ enc, const float* __restrict__ tv,
                         unsigned short* __restrict__ evb)
{
  const int r = blockIdx.x;
  const int bn = r / 48, t = r - bn * 48;
  for (int col = threadIdx.x; col < 448; col += 256) {
    unsigned short o = 0;
    if (col < 387) {
      const int v = col / 129, cc = col - v * 129;
      const float val = (cc < 128) ? enc[(((size_t)bn*3 + v)*48 + t)*128 + cc]
                                   : tv[((size_t)bn*3 + v)*48 + t];
      o = f2b(val);
    }
    evb[(size_t)r*448 + col] = o;
  }
}

__global__ void prep_attb(const float* __restrict__ enc, unsigned short* __restrict__ attb)
{
  const int r = blockIdx.x;
  const int bn = r / 12, q = r - bn * 12;
  for (int col = threadIdx.x; col < 384; col += 256) {
    const int v = col >> 7, cc = col & 127;
    attb[(size_t)r*384 + col] = f2b(enc[(((size_t)bn*3 + v)*48 + 36 + q)*128 + cc]);
  }
}

__global__ void prep_wkv(const float* __restrict__ Wk, const float* __restrict__ Wv,
                         unsigned short* __restrict__ WT)
{
  const int l = blockIdx.y, n = blockIdx.x;
  const int kvs = n >> 9, h = (n >> 6) & 7, d = n & 63;
  const float* src = (kvs ? Wv : Wk) + ((size_t)(l*8 + h)*387)*64 + d;
  unsigned short* dst = WT + ((size_t)l*1024 + n)*448;
  for (int k = threadIdx.x; k < 448; k += 256)
    dst[k] = (k < 387) ? f2b(src[(size_t)k*64]) : 0;
}

__global__ void pad_ab_kernel(unsigned short* __restrict__ ab)
{
  const int r = blockIdx.x;
  if (threadIdx.x < 64) ab[(size_t)r*576 + 512 + threadIdx.x] = 0;
}

__global__ void zero_stats_kernel(float* __restrict__ sraw)
{
  const int i = blockIdx.x * blockDim.x + threadIdx.x;
  if (i < 6*36*2) sraw[i] = 0.f;
}

// ============================================================
// Attention + LN1: 650 blocks x 512 thr; wave h owns head h.
// av/att staged bf16 (77 KB LDS -> 2 blocks/CU).
// ============================================================
__global__ __launch_bounds__(512)
void attn_kernel(const unsigned short* __restrict__ avb, const unsigned short* __restrict__ kvb,
                 const float* __restrict__ lns, const float* __restrict__ lnb,
                 unsigned short* __restrict__ av2b)
{
  const int b = blockIdx.x, tid = threadIdx.x;
  const int h = tid >> 6, lane = tid & 63;
  __shared__ unsigned short avs [12][520];
  __shared__ unsigned short atts[12][520];
  __shared__ unsigned short vsh[8][48][68];

  for (int idx = tid; idx < 12*64; idx += 512) {
    const int v = idx >> 6, c8 = idx & 63;
    *(s8v*)&avs[v][c8*8] = *(const s8v*)(avb + (((size_t)b*12 + v) << 9) + c8*8);
  }
  {
    const int t0 = lane >> 3, c8 = lane & 7;
    #pragma unroll
    for (int i = 0; i < 6; i++) {
      const int t = i*8 + t0;
      *(s8v*)&vsh[h][t][c8*8] =
          *(const s8v*)(kvb + (size_t)(b*48 + t)*1024 + 512 + h*64 + c8*8);
    }
  }
  __syncthreads();

  const int tcl = (lane < 48) ? lane : 0;
  s8v kp[8];
  {
    const unsigned short* kr = kvb + (size_t)(b*48 + tcl)*1024 + h*64;
    #pragma unroll
    for (int i = 0; i < 8; i++) kp[i] = *(const s8v*)(kr + i*8);
  }

  float p[12];
  #pragma unroll
  for (int v = 0; v < 12; v++) p[v] = 0.f;
  #pragma unroll
  for (int k8 = 0; k8 < 8; k8++) {
    float kf[8];
    #pragma unroll
    for (int j = 0; j < 8; j++) kf[j] = b2f((unsigned short)kp[k8][j]);
    #pragma unroll
    for (int v = 0; v < 12; v++) {
      const s8v q8 = *(const s8v*)&avs[v][h*64 + k8*8];
      #pragma unroll
      for (int j = 0; j < 8; j++) p[v] = fmaf(b2f((unsigned short)q8[j]), kf[j], p[v]);
    }
  }
  #pragma unroll
  for (int v = 0; v < 12; v++) {
    const bool valid = (lane < 36 + v);
    float s = valid ? p[v]*0.125f : -1e30f;
    float m = s;
    #pragma unroll
    for (int off = 1; off < 64; off <<= 1) m = fmaxf(m, __shfl_xor(m, off));
    const float e = valid ? expf(s - m) : 0.f;
    float sum = e;
    #pragma unroll
    for (int off = 1; off < 64; off <<= 1) sum += __shfl_xor(sum, off);
    p[v] = e / sum;
  }
  float o[12];
  #pragma unroll
  for (int v = 0; v < 12; v++) o[v] = 0.f;
  #pragma unroll
  for (int t6 = 0; t6 < 6; t6++) {
    float vf[8];
    #pragma unroll
    for (int j = 0; j < 8; j++) vf[j] = b2f(vsh[h][t6*8 + j][lane]);
    #pragma unroll
    for (int j = 0; j < 8; j++) {
      const int tt = t6*8 + j;
      #pragma unroll
      for (int v = 0; v < 12; v++) o[v] = fmaf(__shfl(p[v], tt), vf[j], o[v]);
    }
  }
  #pragma unroll
  for (int v = 0; v < 12; v++) atts[v][h*64 + lane] = f2b(o[v]);
  __syncthreads();

  for (int v = h; v < 12; v += 8) {
    float x[8], sm = 0.f, s2 = 0.f;
    const s8v a8 = *(const s8v*)&avs[v][lane*8];
    const s8v t8 = *(const s8v*)&atts[v][lane*8];
    #pragma unroll
    for (int j = 0; j < 8; j++) {
      const float t = b2f((unsigned short)a8[j]) + b2f((unsigned short)t8[j]);
      x[j] = t; sm += t; s2 += t*t;
    }
    #pragma unroll
    for (int off = 32; off; off >>= 1) { sm += __shfl_xor(sm, off); s2 += __shfl_xor(s2, off); }
    const float mean = sm * (1.f/512.f);
    const float var  = s2 * (1.f/512.f) - mean*mean;
    const float rr = rsqrtf(var + 1e-5f);
    #pragma unroll
    for (int j = 0; j < 8; j++) {
      const int c = lane*8 + j;
      av2b[(((size_t)b*12 + v) << 9) + c] = f2b((x[j] - mean)*rr*lns[c] + lnb[c]);
    }
  }
}

// LN over bf16 rows [7800][512] -> out with stride ldo
__global__ __launch_bounds__(256)
void ln_kernel(const unsigned short* __restrict__ in, unsigned short* __restrict__ out, int ldo,
               const float* __restrict__ s, const float* __restrict__ b)
{
  const int row = blockIdx.x*4 + (threadIdx.x >> 6);
  const int lane = threadIdx.x & 63;
  const s8v xv = *(const s8v*)(in + (size_t)row*512 + lane*8);
  float x[8], sm = 0.f, s2 = 0.f;
  #pragma unroll
  for (int j = 0; j < 8; j++) {
    const float t = b2f((unsigned short)xv[j]);
    x[j] = t; sm += t; s2 += t*t;
  }
  #pragma unroll
  for (int o = 32; o; o >>= 1) { sm += __shfl_xor(sm, o); s2 += __shfl_xor(s2, o); }
  const float mean = sm * (1.f/512.f);
  const float var  = s2 * (1.f/512.f) - mean*mean;
  const float rr = rsqrtf(var + 1e-5f);
  s8v o8;
  #pragma unroll
  for (int j = 0; j < 8; j++) {
    const int c = lane*8 + j;
    o8[j] = (short)f2b((x[j] - mean)*rr*s[c] + b[c]);
  }
  *(s8v*)(out + (size_t)row*ldo + lane*8) = o8;
}

// ============================================================
// NVP small kernels
// ============================================================
__global__ void mu_kernel(const float* __restrict__ tv, const float* __restrict__ u,
                          const float* __restrict__ sab, float* __restrict__ uinf,
                          unsigned short* __restrict__ ab, int blk)
{
  const int r = blockIdx.x*256 + threadIdx.x;
  if (r >= NROWS_) return;
  const int bn = r / 12, q = r - bn * 12;
  float uv[3];
  #pragma unroll
  for (int v = 0; v < 3; v++) {
    if (blk == 0) uv[v] = tv[((size_t)bn*3 + v)*48 + 36 + q];
    else {
      const float a = sab[((blk-1)*36 + q*3 + v)*2 + 0];
      const float c = sab[((blk-1)*36 + q*3 + v)*2 + 1];
      uv[v] = fmaf(a, u[(size_t)r*3 + v], c);
    }
  }
  #pragma unroll
  for (int v = 0; v < 3; v++) {
    uinf[(size_t)r*3 + v] = uv[v];
    ab[(size_t)r*576 + 512 + v] = f2b(((v + blk) & 1) ? uv[v] : 0.f);
  }
}

__global__ __launch_bounds__(512)
void out_couple_kernel(const unsigned short* __restrict__ hs, const unsigned short* __restrict__ ht,
                const float* __restrict__ swo, const float* __restrict__ sbo,
                const float* __restrict__ two, const float* __restrict__ tbo,
                const float* __restrict__ uinf, float* __restrict__ u, float* __restrict__ ld,
                float* __restrict__ sraw, int blk)
{
  __shared__ float sres[4][2][3];
  const int tid = threadIdx.x;
  const int w = tid >> 6, lane = tid & 63;
  const int rloc = w >> 1, net = w & 1;
  const int r = blockIdx.x*4 + rloc;
  const unsigned short* hrow = (net ? ht : hs) + ((size_t)r << 9);
  const float* wo = (net ? two : swo) + (size_t)blk*512*3;

  const s8v hv8 = *(const s8v*)(hrow + lane*8);
  float wbuf[24];
  #pragma unroll
  for (int i = 0; i < 6; i++)
    *(float4*)&wbuf[i*4] = *(const float4*)(wo + lane*24 + i*4);
  float a0 = 0.f, a1 = 0.f, a2 = 0.f;
  #pragma unroll
  for (int i = 0; i < 8; i++) {
    const float hv = b2f((unsigned short)hv8[i]);
    a0 = fmaf(hv, wbuf[i*3+0], a0);
    a1 = fmaf(hv, wbuf[i*3+1], a1);
    a2 = fmaf(hv, wbuf[i*3+2], a2);
  }
  #pragma unroll
  for (int o = 32; o; o >>= 1) {
    a0 += __shfl_xor(a0, o); a1 += __shfl_xor(a1, o); a2 += __shfl_xor(a2, o);
  }
  if (lane == 0) {
    const float* bo = (net ? tbo : sbo) + blk*3;
    sres[rloc][net][0] = a0 + bo[0];
    sres[rloc][net][1] = a1 + bo[1];
    sres[rloc][net][2] = a2 + bo[2];
  }
  __syncthreads();
  if (tid < 12) {
    const int rl = tid / 3, j = tid - 3*rl;
    const int r2 = blockIdx.x*4 + rl;
    const int q = r2 % 12;
    const int msk = (j + blk) & 1;
    const float s = sres[rl][0][j];
    const float t = sres[rl][1][j];
    const float uo = uinf[(size_t)r2*3 + j];
    const float unew = msk ? uo : (uo - t) * expf(-s);
    u[(size_t)r2*3 + j] = unew;
    const float prev = blk ? ld[(size_t)r2*3 + j] : 0.f;
    ld[(size_t)r2*3 + j] = prev - (msk ? 0.f : s);
    atomicAdd(&sraw[(blk*36 + q*3 + j)*2 + 0], unew);
    atomicAdd(&sraw[(blk*36 + q*3 + j)*2 + 1], unew * unew);
  }
}

__global__ void bn_finalize_kernel(const float* __restrict__ sraw, float* __restrict__ sab,
    float* __restrict__ ldadd, const float* __restrict__ lg, const float* __restrict__ bt, int blk)
{
  const int idx = threadIdx.x;
  if (idx < 36) {
    const int v = idx % 3;
    const float sum = sraw[(blk*36 + idx)*2 + 0];
    const float s2  = sraw[(blk*36 + idx)*2 + 1];
    const float bm  = sum * (1.f / 650.f);
    const float bvr = s2 * (1.f / 650.f) - bm * bm;
    const float g = lg[blk*3 + v];
    const float a = expf(g) * rsqrtf(bvr + 1e-5f);
    sab[(blk*36 + idx)*2 + 0] = a;
    sab[(blk*36 + idx)*2 + 1] = bt[blk*3 + v] - a * bm;
    ldadd[blk*36 + idx] = g - 0.5f * logf(bvr + 1e-5f);
  }
}

__global__ void loss_kernel(const float* __restrict__ u, const float* __restrict__ ld,
    const float* __restrict__ sab, const float* __restrict__ ldadd, float* __restrict__ out)
{
  const int bn = blockIdx.x * blockDim.x + threadIdx.x;
  if (bn >= BN_) return;
  float acc = 0.f;
  for (int t2 = 0; t2 < 12; t2++) {
    #pragma unroll
    for (int v = 0; v < 3; v++) {
      const int idx = t2*3 + v;
      const float a = sab[(5*36 + idx)*2 + 0];
      const float c = sab[(5*36 + idx)*2 + 1];
      const float ur = u[((size_t)bn*12 + t2)*3 + v];
      const float ub = fmaf(a, ur, c);
      acc += 0.5f*ub*ub + 0.5f*LOG2PI_ - ld[((size_t)bn*12 + t2)*3 + v];
    }
  }
  float lsum = 0.f;
  for (int i = 0; i < 6*36; i++) lsum += ldadd[i];
  out[bn] = acc - lsum;
}

// ============================================================
// workspace byte offsets
// ============================================================
#define O_WKV    (size_t)0
#define O_WSH    (size_t)3670016
#define O_WFF1   (size_t)4063232
#define O_WFF2   (size_t)6160384
#define O_WSIN   (size_t)8257536
#define O_WTIN   (size_t)11796480
#define O_WSHID  (size_t)15335424
#define O_WTHID  (size_t)27918336
#define O_EVB    (size_t)40501248
#define O_ATTB   (size_t)68456448
#define O_AVB    (size_t)74446848
#define O_AV2B   (size_t)82434048
#define O_HB     (size_t)90421248
#define O_FFSUM  (size_t)98408448
#define O_KVB    (size_t)106395648
#define O_AB     O_KVB
#define O_HS0    (O_KVB + 8985600)
#define O_HS1    (O_HS0 + 7987200)
#define O_HT0    (O_HS1 + 7987200)
#define O_HT1    (O_HT0 + 7987200)
#define O_UINF   (size_t)170293248
#define O_U      (size_t)170386848
#define O_LD     (size_t)170480448
#define O_SRAW   (size_t)170761248
#define O_SAB    (size_t)170762976
#define O_LDA    (size_t)170764704

static inline GZ mkgz(const void* A, const void* B, const float* bias, void* C,
                      const void* res, int act) {
  GZ g; g.A = (const unsigned short*)A; g.B = (const unsigned short*)B; g.bias = bias;
  g.C = (unsigned short*)C; g.res = (const unsigned short*)res; g.act = act; return g;
}

extern "C" void kernel_launch(void* const* d_in, const int* in_sizes, int n_in,
                              void* d_out, int out_size, void* d_ws, size_t ws_size,
                              hipStream_t stream)
{
  const float* enc   = (const float*)d_in[0];
  const float* tv    = (const float*)d_in[1];
  const float* Wsh   = (const float*)d_in[2];
  const float* bsh   = (const float*)d_in[3];
  const float* Wk    = (const float*)d_in[4];
  const float* bk    = (const float*)d_in[5];
  const float* Wv    = (const float*)d_in[6];
  const float* bv    = (const float*)d_in[7];
  const float* ln1s  = (const float*)d_in[8];
  const float* ln1b  = (const float*)d_in[9];
  const float* fw1   = (const float*)d_in[10];
  const float* fb1   = (const float*)d_in[11];
  const float* fw2   = (const float*)d_in[12];
  const float* fb2   = (const float*)d_in[13];
  const float* ln2s  = (const float*)d_in[14];
  const float* ln2b  = (const float*)d_in[15];
  const float* swin  = (const float*)d_in[16];
  const float* sbin  = (const float*)d_in[17];
  const float* swhid = (const float*)d_in[18];
  const float* sbhid = (const float*)d_in[19];
  const float* swout = (const float*)d_in[20];
  const float* sbout = (const float*)d_in[21];
  const float* twin  = (const float*)d_in[22];
  const float* tbin  = (const float*)d_in[23];
  const float* twhid = (const float*)d_in[24];
  const float* tbhid = (const float*)d_in[25];
  const float* twout = (const float*)d_in[26];
  const float* tbout = (const float*)d_in[27];
  const float* bnlg  = (const float*)d_in[28];
  const float* bnbt  = (const float*)d_in[29];

  char* ws = (char*)d_ws;
  unsigned short* wkv   = (unsigned short*)(ws + O_WKV);
  unsigned short* wsht  = (unsigned short*)(ws + O_WSH);
  unsigned short* wff1t = (unsigned short*)(ws + O_WFF1);
  unsigned short* wff2t = (unsigned short*)(ws + O_WFF2);
  unsigned short* wsint = (unsigned short*)(ws + O_WSIN);
  unsigned short* wtint = (unsigned short*)(ws + O_WTIN);
  unsigned short* wshid = (unsigned short*)(ws + O_WSHID);
  unsigned short* wthid = (unsigned short*)(ws + O_WTHID);
  unsigned short* evb   = (unsigned short*)(ws + O_EVB);
  unsigned short* attb  = (unsigned short*)(ws + O_ATTB);
  unsigned short* avb   = (unsigned short*)(ws + O_AVB);
  unsigned short* av2b  = (unsigned short*)(ws + O_AV2B);
  unsigned short* hb    = (unsigned short*)(ws + O_HB);
  unsigned short* ffsum = (unsigned short*)(ws + O_FFSUM);
  unsigned short* kvb   = (unsigned short*)(ws + O_KVB);
  unsigned short* ab    = (unsigned short*)(ws + O_AB);
  unsigned short* hs0   = (unsigned short*)(ws + O_HS0);
  unsigned short* hs1   = (unsigned short*)(ws + O_HS1);
  unsigned short* ht0   = (unsigned short*)(ws + O_HT0);
  unsigned short* ht1   = (unsigned short*)(ws + O_HT1);
  float* uinf  = (float*)(ws + O_UINF);
  float* u     = (float*)(ws + O_U);
  float* ld    = (float*)(ws + O_LD);
  float* sraw  = (float*)(ws + O_SRAW);
  float* sab   = (float*)(ws + O_SAB);
  float* lda   = (float*)(ws + O_LDA);
  float* out   = (float*)d_out;

  // ---- prep: activations ----
  prep_evb<<<MKV_, 256, 0, stream>>>(enc, tv, evb);
  prep_attb<<<NROWS_, 256, 0, stream>>>(enc, attb);
  prep_wkv<<<dim3(1024, 4), 256, 0, stream>>>(Wk, Wv, wkv);
  // ---- prep: coalesced tiled weight transposes ----
  trans_w<<<dim3(6*8, 1),  256, 0, stream>>>(Wsh,  wsht,  384, 512, 384, 6,
      (size_t)0, (size_t)0);
  trans_w<<<dim3(8*8, 4),  256, 0, stream>>>(fw1,  wff1t, 512, 512, 512, 8,
      (size_t)512*512, (size_t)512*512);
  trans_w<<<dim3(8*8, 4),  256, 0, stream>>>(fw2,  wff2t, 512, 512, 512, 8,
      (size_t)512*512, (size_t)512*512);
  trans_w<<<dim3(9*8, 6),  256, 0, stream>>>(swin, wsint, 515, 512, 576, 9,
      (size_t)515*512, (size_t)512*576);
  trans_w<<<dim3(9*8, 6),  256, 0, stream>>>(twin, wtint, 515, 512, 576, 9,
      (size_t)515*512, (size_t)512*576);
  trans_w<<<dim3(8*8, 24), 256, 0, stream>>>(swhid, wshid, 512, 512, 512, 8,
      (size_t)512*512, (size_t)512*512);
  trans_w<<<dim3(8*8, 24), 256, 0, stream>>>(twhid, wthid, 512, 512, 512, 8,
      (size_t)512*512, (size_t)512*512);
  zero_stats_kernel<<<2, 256, 0, stream>>>(sraw);

  const GZ gnull = mkgz(nullptr, nullptr, nullptr, nullptr, nullptr, 0);

  // ---- shift GEMM ----
  {
    GZ g = mkgz(attb, wsht, bsh, avb, nullptr, 0);
    gemm_bf16<128><<<dim3(4, 61, 1), 256, 0, stream>>>(g, gnull, NROWS_, 384);
  }

  // ---- transformer layers ----
  for (int l = 0; l < 4; l++) {
    gemm_kv<<<244, 512, 0, stream>>>(evb, wkv + (size_t)l*1024*448,
        bk + l*512, bv + l*512, kvb, MKV_);
    attn_kernel<<<BN_, 512, 0, stream>>>(avb, kvb, ln1s + l*512, ln1b + l*512, av2b);
    GZ g1 = mkgz(av2b, wff1t + (size_t)l*512*512, fb1 + l*512, hb, nullptr, 1);
    gemm_bf16<128><<<dim3(4, 61, 1), 256, 0, stream>>>(g1, gnull, NROWS_, 512);
    GZ g2 = mkgz(hb, wff2t + (size_t)l*512*512, fb2 + l*512, ffsum, av2b, 0);
    gemm_bf16<128><<<dim3(4, 61, 1), 256, 0, stream>>>(g2, gnull, NROWS_, 512);
    if (l == 3)
      ln_kernel<<<1950, 256, 0, stream>>>(ffsum, ab, 576, ln2s + l*512, ln2b + l*512);
    else
      ln_kernel<<<1950, 256, 0, stream>>>(ffsum, avb, 512, ln2s + l*512, ln2b + l*512);
  }

  // ---- RealNVP (128x128 tiles, 488-block grids) ----
  pad_ab_kernel<<<NROWS_, 64, 0, stream>>>(ab);
  for (int blk = 0; blk < 6; blk++) {
    mu_kernel<<<31, 256, 0, stream>>>(tv, u, sab, uinf, ab, blk);
    {
      GZ gs = mkgz(ab, wsint + (size_t)blk*512*576, sbin + blk*512, hs0, nullptr, 2);
      GZ gt = mkgz(ab, wtint + (size_t)blk*512*576, tbin + blk*512, ht0, nullptr, 1);
      gemm_bf16<128><<<dim3(4, 61, 2), 256, 0, stream>>>(gs, gt, NROWS_, 576);
    }
    for (int i = 0; i < 4; i++) {
      unsigned short* srcs = (i & 1) ? hs1 : hs0;
      unsigned short* dsts = (i & 1) ? hs0 : hs1;
      unsigned short* srct = (i & 1) ? ht1 : ht0;
      unsigned short* dstt = (i & 1) ? ht0 : ht1;
      GZ gs = mkgz(srcs, wshid + (size_t)(blk*4 + i)*512*512, sbhid + (blk*4 + i)*512, dsts, nullptr, 2);
      GZ gt = mkgz(srct, wthid + (size_t)(blk*4 + i)*512*512, tbhid + (blk*4 + i)*512, dstt, nullptr, 1);
      gemm_bf16<128><<<dim3(4, 61, 2), 256, 0, stream>>>(gs, gt, NROWS_, 512);
    }
    out_couple_kernel<<<1950, 512, 0, stream>>>(hs0, ht0, swout, sbout, twout, tbout,
        uinf, u, ld, sraw, blk);
    bn_finalize_kernel<<<1, 64, 0, stream>>>(sraw, sab, lda, bnlg, bnbt, blk);
  }
  loss_kernel<<<3, 256, 0, stream>>>(u, ld, sab, lda, out);
}